// Round 8
// baseline (4769.970 us; speedup 1.0000x reference)
//
#include <hip/hip_runtime.h>
#include <stdint.h>

#define B_TOTAL 1024
#define T_STEPS 128
#define F_DIM   64
#define H_DIM   256
#define BROWS   16
#define APAD    324   // A_lds row stride in shorts (648 B)
#define ZPAD    260   // z_lds row stride in floats
#define NSLOTS  640   // 4 cgroups * 8 waves * 20 frags; slot = (c*8+w)*20 + kt*2 + nt

typedef float f32x4 __attribute__((ext_vector_type(4)));
typedef short bf16x8 __attribute__((ext_vector_type(8)));

__device__ __forceinline__ unsigned short f2bf(float f) {
  unsigned int u = __float_as_uint(f);
  u += 0x7fffu + ((u >> 16) & 1u);
  return (unsigned short)(u >> 16);
}
__device__ __forceinline__ float bf2f(unsigned short b) {
  return __uint_as_float(((unsigned int)b) << 16);
}
__device__ __forceinline__ float sigmoid_f(float x) {
  return 1.0f / (1.0f + __expf(-x));
}
__device__ __forceinline__ float tanh_f(float x) {
  return 1.0f - 2.0f / (1.0f + __expf(2.0f * x));
}

// Pack kernel weights (320x1024 fp32 row-major) into bf16 MFMA-B fragments.
// slot = (c*8 + w)*20 + kt*2 + nt ; p = w*2+nt ; ntile = (p>>2)*16 + c*4 + (p&3)
// Wp[(slot*64 + l)*8 + j] = W[kt*32 + 8*(l>>4) + j][ntile*16 + (l&15)]
__global__ __launch_bounds__(64) void pack_w_kernel(const float* __restrict__ W,
                                                    unsigned short* __restrict__ Wp) {
  const int slot = blockIdx.x;
  const int cw = slot / 20;            // c*8 + w
  const int k2 = slot % 20;
  const int kt = k2 >> 1, nt = k2 & 1;
  const int c  = cw >> 3, w = cw & 7;
  const int p  = w * 2 + nt;
  const int ntile = ((p >> 2) << 4) + (c << 2) + (p & 3);
  const int l   = threadIdx.x;
  const int col = ntile * 16 + (l & 15);
  const int k0  = kt * 32 + (l >> 4) * 8;
  unsigned short* dst = Wp + ((size_t)slot * 64 + l) * 8;
  #pragma unroll
  for (int j = 0; j < 8; ++j)
    dst[j] = f2bf(W[(size_t)(k0 + j) * 1024 + col]);
}

// Opaque pin: un-rematerializable def -> weight frags stay in VGPRs.
#define PIN(x) asm volatile("" : "+v"(x))
#define LD_A(kt) (*(const bf16x8*)&A_lds[cl][(kt) * 32 + kg * 8])

// 256 blocks (= CU count, 1 block/CU -> all co-resident), 512 threads.
// Block bid: c = bid>>6 (column group, 64 h-cols), g = bid&63 (16 batch rows).
// Partners {g, 64+g, 128+g, 192+g} differ by multiples of 64 -> same bid%8 (XCD).
__global__ __launch_bounds__(512, 1) void qlstm_kernel(
    const float* __restrict__ history, const float* __restrict__ head,
    const float* __restrict__ bias,
    const float* __restrict__ w_i, const float* __restrict__ w_f, const float* __restrict__ w_o,
    const unsigned short* __restrict__ Wp,
    const float* __restrict__ fc3_w, const float* __restrict__ fc3_b,
    const float* __restrict__ fc4_w, const float* __restrict__ fc4_b,
    const float* __restrict__ sell_v_w, const float* __restrict__ sell_v_b,
    const float* __restrict__ sell_q_w, const float* __restrict__ sell_q_b,
    const float* __restrict__ buy_v_w, const float* __restrict__ buy_v_b,
    const float* __restrict__ buy_q_w, const float* __restrict__ buy_q_b,
    float* __restrict__ out,
    unsigned int* __restrict__ slices,   // [2 parity][64 g][4 c][512 uints] (2KB slices)
    unsigned int* __restrict__ flags) {  // [129][256], zeroed each launch

  __shared__ unsigned short A_lds[BROWS][APAD];  // [r][k] bf16: k<64 = x_t, 64..319 = h_t
  __shared__ float z_lds[BROWS][ZPAD];           // block-local z: [r][gate*64 + hcol_local]
  __shared__ float feat[BROWS][258];
  __shared__ float v_l[BROWS][128];
  __shared__ float q_l[BROWS][128];
  __shared__ float ispos[BROWS];

  const int tid = threadIdx.x;
  const int w   = tid >> 6;        // wave 0..7
  const int l   = tid & 63;
  const int cl  = l & 15;          // A-row / z-col-in-tile
  const int kg  = l >> 4;          // 0..3
  const int bid = blockIdx.x;
  const int c   = bid >> 6;        // column group 0..3
  const int g   = bid & 63;        // batch group 0..63
  const int rb  = g * BROWS;
  const int r_t = tid >> 5;        // row 0..15 (gate/slice/x ops)
  const int x0c = (tid & 31) * 2;  // x col (even)
  const int hc0 = (2 * tid) & 63;  // local h col (even); thread owns (r_t, hc0..hc0+1)

  // ---- weights: fully register-resident (20 frags = 80 VGPRs), pinned ----
  const unsigned short* wp_wl = Wp + ((size_t)((c << 3) + w) * 20) * 512 + l * 8;
  bf16x8 wreg[10][2];
  #pragma unroll
  for (int kt = 0; kt < 10; ++kt)
    #pragma unroll
    for (int nt = 0; nt < 2; ++nt) {
      wreg[kt][nt] = *(const bf16x8*)(wp_wl + (kt * 2 + nt) * 512);
      PIN(wreg[kt][nt]);
    }

  // ---- zero A (h_0 = 0), stage x_0 ----
  for (int i = tid; i < BROWS * APAD; i += 512)
    ((unsigned short*)A_lds)[i] = 0;
  __syncthreads();
  {
    const float2 xv0 = *(const float2*)&history[((size_t)(rb + r_t) * T_STEPS + 0) * F_DIM + x0c];
    *(unsigned int*)&A_lds[r_t][x0c] =
        (unsigned int)f2bf(xv0.x) | ((unsigned int)f2bf(xv0.y) << 16);
  }

  // ---- per-thread gate constants (2 h-cols) ----
  const int hcg = (c << 6) + hc0;
  const float2 wi2 = *(const float2*)&w_i[hcg];
  const float2 wf2 = *(const float2*)&w_f[hcg];
  const float2 wo2 = *(const float2*)&w_o[hcg];
  float2 b2[4];
  #pragma unroll
  for (int g2 = 0; g2 < 4; ++g2) b2[g2] = *(const float2*)&bias[g2 * 256 + hcg];

  float2 cst; cst.x = 0.0f; cst.y = 0.0f;
  __syncthreads();

  // ---- the scan ----
  for (int t = 0; t < T_STEPS; ++t) {
    const bool havex = (t + 1 < T_STEPS);
    float2 xv; xv.x = 0.0f; xv.y = 0.0f;
    if (havex)
      xv = *(const float2*)&history[((size_t)(rb + r_t) * T_STEPS + (t + 1)) * F_DIM + x0c];

    // MFMA: 2 ntiles/wave x 10 kt, weights from registers
    f32x4 acc0 = (f32x4){0.f, 0.f, 0.f, 0.f};
    f32x4 acc1 = (f32x4){0.f, 0.f, 0.f, 0.f};
    #pragma unroll
    for (int kt = 0; kt < 10; ++kt) {
      const bf16x8 af = LD_A(kt);
      acc0 = __builtin_amdgcn_mfma_f32_16x16x32_bf16(af, wreg[kt][0], acc0, 0, 0, 0);
      acc1 = __builtin_amdgcn_mfma_f32_16x16x32_bf16(af, wreg[kt][1], acc1, 0, 0, 0);
    }
    // dump z to LDS (C layout: row=(l>>4)*4+q, col=l&15)
    {
      const int p0 = w * 2, p1 = w * 2 + 1;
      const int cb0 = ((p0 >> 2) << 6) + ((p0 & 3) << 4) + cl;
      const int cb1 = ((p1 >> 2) << 6) + ((p1 & 3) << 4) + cl;
      #pragma unroll
      for (int q = 0; q < 4; ++q) {
        z_lds[kg * 4 + q][cb0] = acc0[q];
        z_lds[kg * 4 + q][cb1] = acc1[q];
      }
    }
    __syncthreads();  // (1) z ready; A_lds step-t reads done

    // gates: thread owns (r_t, hc0), (r_t, hc0+1)
    const float2 zi = *(const float2*)&z_lds[r_t][hc0];
    const float2 zj = *(const float2*)&z_lds[r_t][64 + hc0];
    const float2 zf = *(const float2*)&z_lds[r_t][128 + hc0];
    const float2 zo = *(const float2*)&z_lds[r_t][192 + hc0];
    const float i0 = sigmoid_f(zi.x + b2[0].x + wi2.x * cst.x);
    const float f0 = sigmoid_f(zf.x + b2[2].x + 1.0f + wf2.x * cst.x);
    const float j0 = tanh_f(zj.x + b2[1].x);
    const float cn0 = f0 * cst.x + i0 * j0;
    const float o0 = sigmoid_f(zo.x + b2[3].x + wo2.x * cn0);
    const float h0 = o0 * tanh_f(cn0);
    const float i1 = sigmoid_f(zi.y + b2[0].y + wi2.y * cst.y);
    const float f1 = sigmoid_f(zf.y + b2[2].y + 1.0f + wf2.y * cst.y);
    const float j1 = tanh_f(zj.y + b2[1].y);
    const float cn1 = f1 * cst.y + i1 * j1;
    const float o1 = sigmoid_f(zo.y + b2[3].y + wo2.y * cn1);
    const float h1 = o1 * tanh_f(cn1);
    cst.x = cn0; cst.y = cn1;

    const unsigned int hpack = (unsigned int)f2bf(h0) | ((unsigned int)f2bf(h1) << 16);
    *(unsigned int*)&A_lds[r_t][64 + (c << 6) + hc0] = hpack;  // own slice -> LDS

    // publish own slice (agent-coherent), then flag
    const int par = (t + 1) & 1;
    __hip_atomic_store(slices + ((((par << 6) + g) << 2) + c) * 512 + tid, hpack,
                       __ATOMIC_RELAXED, __HIP_MEMORY_SCOPE_AGENT);
    __threadfence();
    __syncthreads();  // (2) all slice stores fenced
    if (tid == 0)
      __hip_atomic_store(&flags[(t + 1) * 256 + bid], 1u,
                         __ATOMIC_RELEASE, __HIP_MEMORY_SCOPE_AGENT);

    if (t == T_STEPS - 1 && c != 0) break;  // non-epilogue blocks done

    // wait for the 3 partners, then pull their slices
    if (tid < 3) {
      const int pc = tid + (tid >= c ? 1 : 0);
      while (__hip_atomic_load(&flags[(t + 1) * 256 + (pc << 6) + g],
                               __ATOMIC_ACQUIRE, __HIP_MEMORY_SCOPE_AGENT) == 0u)
        __builtin_amdgcn_s_sleep(1);
    }
    __syncthreads();  // (3) partners published

    #pragma unroll
    for (int pp = 0; pp < 3; ++pp) {
      const int pc = pp + (pp >= c ? 1 : 0);
      const unsigned int v = __hip_atomic_load(
          slices + ((((par << 6) + g) << 2) + pc) * 512 + tid,
          __ATOMIC_RELAXED, __HIP_MEMORY_SCOPE_AGENT);
      *(unsigned int*)&A_lds[r_t][64 + (pc << 6) + hc0] = v;
    }
    if (havex)
      *(unsigned int*)&A_lds[r_t][x0c] =
          (unsigned int)f2bf(xv.x) | ((unsigned int)f2bf(xv.y) << 16);
    __syncthreads();  // (4) h_{t+1}, x_{t+1} assembled
  }

  if (c != 0) return;

  // ---- epilogue (c==0 blocks only; full h_T assembled in A_lds) ----
  for (int i = tid; i < BROWS * H_DIM; i += 512) {
    const int r = i >> 8, hc = i & 255;
    feat[r][2 + hc] = bf2f(A_lds[r][64 + hc]);
  }
  if (tid < BROWS) {
    feat[tid][0] = head[(rb + tid) * 3 + 1];
    feat[tid][1] = head[(rb + tid) * 3 + 2];
    ispos[tid] = head[(rb + tid) * 3 + 0];
  }
  __syncthreads();

  #pragma unroll
  for (int p = 0; p < 4; ++p) {
    const int idx = p * 512 + tid;
    const int r = idx >> 7, hh = idx & 127;
    float s3 = fc3_b[hh], s4 = fc4_b[hh];
    for (int k = 0; k < 258; ++k) {
      const float fv = feat[r][k];
      s3 += fv * fc3_w[k * 128 + hh];
      s4 += fv * fc4_w[k * 128 + hh];
    }
    v_l[r][hh] = fmaxf(s3, 0.0f);
    q_l[r][hh] = fmaxf(s4, 0.0f);
  }
  __syncthreads();

  if (tid < BROWS) {
    const int r = tid;
    float pa0 = sell_q_b[0], pa1 = sell_q_b[1];
    float ea0 = buy_q_b[0],  ea1 = buy_q_b[1];
    float sv = sell_v_b[0], bv = buy_v_b[0];
    for (int hh = 0; hh < 128; ++hh) {
      const float qv = q_l[r][hh], vv = v_l[r][hh];
      pa0 += qv * sell_q_w[hh * 2 + 0];
      pa1 += qv * sell_q_w[hh * 2 + 1];
      ea0 += qv * buy_q_w[hh * 2 + 0];
      ea1 += qv * buy_q_w[hh * 2 + 1];
      sv += vv * sell_v_w[hh];
      bv += vv * buy_v_w[hh];
    }
    const float pm = 0.5f * (pa0 + pa1), em = 0.5f * (ea0 + ea1);
    const float pq0 = pa0 - pm + sv, pq1 = pa1 - pm + sv;
    const float eq0 = ea0 - em + bv, eq1 = ea1 - em + bv;
    const float ip = ispos[r];
    out[(size_t)(rb + r) * 2 + 0] = (ip != 0.0f) ? pq0 : eq0;
    out[(size_t)(rb + r) * 2 + 1] = ((1.0f - ip) != 0.0f) ? pq1 : eq1;
  }
}

extern "C" void kernel_launch(void* const* d_in, const int* in_sizes, int n_in,
                              void* d_out, int out_size, void* d_ws, size_t ws_size,
                              hipStream_t stream) {
  (void)in_sizes; (void)n_in; (void)out_size; (void)ws_size;
  const float* history  = (const float*)d_in[0];
  const float* head     = (const float*)d_in[1];
  const float* Wk       = (const float*)d_in[2];
  const float* bias     = (const float*)d_in[3];
  const float* w_i      = (const float*)d_in[4];
  const float* w_f      = (const float*)d_in[5];
  const float* w_o      = (const float*)d_in[6];
  const float* fc3_w    = (const float*)d_in[7];
  const float* fc3_b    = (const float*)d_in[8];
  const float* fc4_w    = (const float*)d_in[9];
  const float* fc4_b    = (const float*)d_in[10];
  const float* sell_v_w = (const float*)d_in[11];
  const float* sell_v_b = (const float*)d_in[12];
  const float* sell_q_w = (const float*)d_in[13];
  const float* sell_q_b = (const float*)d_in[14];
  const float* buy_v_w  = (const float*)d_in[15];
  const float* buy_v_b  = (const float*)d_in[16];
  const float* buy_q_w  = (const float*)d_in[17];
  const float* buy_q_b  = (const float*)d_in[18];

  // workspace layout: Wp (640 KiB) | slices (1 MiB) | flags (132 KiB)
  unsigned short* Wp     = (unsigned short*)d_ws;
  unsigned int*   slices = (unsigned int*)((char*)d_ws + (size_t)NSLOTS * 1024);
  unsigned int*   flags  = (unsigned int*)((char*)d_ws + (size_t)NSLOTS * 1024 + 2 * 64 * 4 * 2048);

  hipMemsetAsync(flags, 0, (size_t)(T_STEPS + 1) * 256 * sizeof(unsigned int), stream);
  pack_w_kernel<<<NSLOTS, 64, 0, stream>>>(Wk, Wp);
  qlstm_kernel<<<256, 512, 0, stream>>>(
      history, head, bias, w_i, w_f, w_o, Wp,
      fc3_w, fc3_b, fc4_w, fc4_b,
      sell_v_w, sell_v_b, sell_q_w, sell_q_b,
      buy_v_w, buy_v_b, buy_q_w, buy_q_b,
      (float*)d_out, slices, flags);
}

// Round 9
// 790.057 us; speedup vs baseline: 6.0375x; 6.0375x over previous
//
#include <hip/hip_runtime.h>
#include <stdint.h>

#define B_TOTAL 1024
#define T_STEPS 128
#define F_DIM   64
#define H_DIM   256
#define BROWS   16
#define APAD    324   // row stride 648B
#define NSLOTS  640   // 8 waves * 80 frags; slot = w*80 + kt*8 + ct*4 + g

typedef float f32x4 __attribute__((ext_vector_type(4)));
typedef short bf16x8 __attribute__((ext_vector_type(8)));

__device__ __forceinline__ unsigned short f2bf(float f) {
  unsigned int u = __float_as_uint(f);
  u += 0x7fffu + ((u >> 16) & 1u);
  return (unsigned short)(u >> 16);
}
__device__ __forceinline__ float bf2f(unsigned short b) {
  return __uint_as_float(((unsigned int)b) << 16);
}
__device__ __forceinline__ float sigmoid_f(float x) {
  return 1.0f / (1.0f + __expf(-x));
}
__device__ __forceinline__ float tanh_f(float x) {
  return 1.0f - 2.0f / (1.0f + __expf(2.0f * x));
}

// Pack kernel weights (320x1024 fp32 row-major) into bf16 MFMA-B fragments,
// wave-major: slot = w*80 + kt*8 + ct*4 + g; ntile = g*16 + w*2 + ct.
__global__ __launch_bounds__(64) void pack_w_kernel(const float* __restrict__ W,
                                                    unsigned short* __restrict__ Wp) {
  const int slot = blockIdx.x;
  const int w  = slot / 80, r = slot % 80;
  const int kt = r >> 3, ct = (r >> 2) & 1, g = r & 3;
  const int ntile = g * 16 + w * 2 + ct;
  const int l   = threadIdx.x;
  const int col = ntile * 16 + (l & 15);
  const int k0  = kt * 32 + (l >> 4) * 8;
  unsigned short* dst = Wp + ((size_t)slot * 64 + l) * 8;
  #pragma unroll
  for (int j = 0; j < 8; ++j)
    dst[j] = f2bf(W[(size_t)(k0 + j) * 1024 + col]);
}

// Opaque pin: un-rematerializable def -> stays in unified VGPR/AGPR file.
#define PIN(x) asm volatile("" : "+v"(x))

// Issue 4 streamed fragments of (kt,ct). Proven addressing:
// Wp is shorts, one frag slot = 512 shorts; f = kt*8 + ct*4 + g.
// Buffers live ONLY within one loop iteration (no loop-carried async regs).
#define ISSUE_BATCH(buf, kt, ct) do {                                        \
    const unsigned short* _p = wp_wl + ((kt) * 8 + (ct) * 4) * 512;          \
    asm volatile("global_load_dwordx4 %0, %4, off\n\t"                       \
                 "global_load_dwordx4 %1, %4, off offset:1024\n\t"           \
                 "global_load_dwordx4 %2, %4, off offset:2048\n\t"           \
                 "global_load_dwordx4 %3, %4, off offset:3072"               \
                 : "=&v"(buf[0]), "=&v"(buf[1]), "=&v"(buf[2]), "=&v"(buf[3])\
                 : "v"(_p));                                                 \
  } while (0)

// Counted wait + sched fences (rule #18), 4 MFMAs into acc[ct].
#define CONSUME_S(buf, ct, afv, N) do {                                      \
    asm volatile("s_waitcnt vmcnt(" #N ")" ::: "memory");                    \
    __builtin_amdgcn_sched_barrier(0);                                       \
    acc[ct][0] = __builtin_amdgcn_mfma_f32_16x16x32_bf16(afv, buf[0], acc[ct][0], 0, 0, 0); \
    acc[ct][1] = __builtin_amdgcn_mfma_f32_16x16x32_bf16(afv, buf[1], acc[ct][1], 0, 0, 0); \
    acc[ct][2] = __builtin_amdgcn_mfma_f32_16x16x32_bf16(afv, buf[2], acc[ct][2], 0, 0, 0); \
    acc[ct][3] = __builtin_amdgcn_mfma_f32_16x16x32_bf16(afv, buf[3], acc[ct][3], 0, 0, 0); \
    __builtin_amdgcn_sched_barrier(0);                                       \
  } while (0)

#define LD_A(kt) (*(const bf16x8*)&A_lds[cl][(kt) * 32 + kg * 8])

__global__ __launch_bounds__(512, 1) void qlstm_kernel(
    const float* __restrict__ history, const float* __restrict__ head,
    const float* __restrict__ bias,
    const float* __restrict__ w_i, const float* __restrict__ w_f, const float* __restrict__ w_o,
    const unsigned short* __restrict__ Wp,
    const float* __restrict__ fc3_w, const float* __restrict__ fc3_b,
    const float* __restrict__ fc4_w, const float* __restrict__ fc4_b,
    const float* __restrict__ sell_v_w, const float* __restrict__ sell_v_b,
    const float* __restrict__ sell_q_w, const float* __restrict__ sell_q_b,
    const float* __restrict__ buy_v_w, const float* __restrict__ buy_v_b,
    const float* __restrict__ buy_q_w, const float* __restrict__ buy_q_b,
    float* __restrict__ out) {

  __shared__ unsigned short A_lds[BROWS][APAD];   // bf16: [r][k], k<64 = x_t, 64..319 = h
  __shared__ unsigned short W_lds[128 * 512];     // 128 KiB: kt5,6; slot s = w*16 + (kt-5)*8 + ct*4 + g

  const int tid = threadIdx.x;
  const int w   = tid >> 6;       // wave 0..7
  const int l   = tid & 63;
  const int cl  = l & 15;         // A-row / acc-col
  const int kg  = l >> 4;         // 0..3
  const int rb  = blockIdx.x * BROWS;

  const unsigned short* wp_wl = Wp + (size_t)(w * 80) * 512 + l * 8;
  const unsigned short* wl_l  = W_lds + (w * 16) * 512 + l * 8;

  // ---- preload LDS weight tier: frags f=40..55 (kt5,6) per wave ----
  for (int i = tid; i < 128 * 64; i += 512) {
    const int s = i >> 6, l2 = i & 63;
    const int fsrc = (s >> 4) * 80 + 40 + (s & 15);   // = w*80 + kt*8+ct*4+g, kt in {5,6}
    *(uint4*)&W_lds[((size_t)s * 64 + l2) * 8] =
        *(const uint4*)&Wp[((size_t)fsrc * 64 + l2) * 8];
  }

  // ---- register tier: kt 0..4 (40 frags = 160 regs), pinned ----
  bf16x8 wreg[5][2][4];
  #pragma unroll
  for (int kt = 0; kt < 5; ++kt)
    #pragma unroll
    for (int ct = 0; ct < 2; ++ct)
      #pragma unroll
      for (int g = 0; g < 4; ++g) {
        wreg[kt][ct][g] = *(const bf16x8*)(wp_wl + (kt * 8 + ct * 4 + g) * 512);
        PIN(wreg[kt][ct][g]);
      }

  // ---- zero A, stage x_0 ----
  for (int i = tid; i < BROWS * APAD; i += 512)
    ((unsigned short*)A_lds)[i] = 0;
  __syncthreads();
  {
    const int r  = tid >> 5;
    const int f0 = (tid & 31) * 2;
    const float2 xv0 = *(const float2*)&history[((size_t)(rb + r) * T_STEPS + 0) * F_DIM + f0];
    *(unsigned int*)&A_lds[r][f0] =
        (unsigned int)f2bf(xv0.x) | ((unsigned int)f2bf(xv0.y) << 16);
  }

  // ---- per-lane gate constants ----
  float bias_r[2][4], wi_r[2], wf_r[2], wo_r[2];
  #pragma unroll
  for (int ct = 0; ct < 2; ++ct) {
    const int hc = (w * 2 + ct) * 16 + cl;
    wi_r[ct] = w_i[hc]; wf_r[ct] = w_f[hc]; wo_r[ct] = w_o[hc];
    #pragma unroll
    for (int g = 0; g < 4; ++g) bias_r[ct][g] = bias[g * 256 + hc];
  }

  float c_st[2][4];
  #pragma unroll
  for (int ct = 0; ct < 2; ++ct)
    #pragma unroll
    for (int q = 0; q < 4; ++q) c_st[ct][q] = 0.0f;

  __syncthreads();

  // ---- the scan. All stream state is iteration-local (proven structure). ----
  for (int t = 0; t < T_STEPS; ++t) {
    // x prefetch for t+1: issued FIRST -> oldest in vmcnt queue, retired by
    // the first vmcnt(4) below.
    float2 xv;
    const bool havex = (t + 1 < T_STEPS);
    if (havex) {
      const float* xp =
          &history[((size_t)(rb + (tid >> 5)) * T_STEPS + (t + 1)) * F_DIM + (tid & 31) * 2];
      asm volatile("global_load_dwordx2 %0, %1, off" : "=&v"(xv) : "v"(xp));
    }

    f32x4 acc[2][4];
    #pragma unroll
    for (int ct = 0; ct < 2; ++ct)
      #pragma unroll
      for (int g = 0; g < 4; ++g)
        acc[ct][g] = (f32x4){0.f, 0.f, 0.f, 0.f};

    // stream tier = kt7..9 (6 batches), 2 buffers, in-iteration
    bf16x8 sA[4], sB[4];
    ISSUE_BATCH(sA, 7, 0);
    ISSUE_BATCH(sB, 7, 1);

    // reg tier kt0..4 (covers L2 latency of the first batches)
    #pragma unroll
    for (int kt = 0; kt < 5; ++kt) {
      const bf16x8 afr = LD_A(kt);
      #pragma unroll
      for (int ct = 0; ct < 2; ++ct)
        #pragma unroll
        for (int g = 0; g < 4; ++g)
          acc[ct][g] =
              __builtin_amdgcn_mfma_f32_16x16x32_bf16(afr, wreg[kt][ct][g], acc[ct][g], 0, 0, 0);
    }

    // LDS tier kt5..6 (LDS pipe, parallel to the stream)
    #pragma unroll
    for (int kt = 5; kt < 7; ++kt) {
      const bf16x8 afr = LD_A(kt);
      #pragma unroll
      for (int ct = 0; ct < 2; ++ct)
        #pragma unroll
        for (int g = 0; g < 4; ++g) {
          const bf16x8 b = *(const bf16x8*)(wl_l + ((kt - 5) * 8 + ct * 4 + g) * 512);
          acc[ct][g] = __builtin_amdgcn_mfma_f32_16x16x32_bf16(afr, b, acc[ct][g], 0, 0, 0);
        }
    }

    // ladder: A,B alternation; each ISSUE refills the just-consumed buffer.
    // vmcnt trace: start 9 (x+sA+sB) -> each consume waits 4, each issue +4;
    // drains to 0 before the barrier.
    bf16x8 af;
    af = LD_A(7);
    CONSUME_S(sA, 0, af, 4); ISSUE_BATCH(sA, 8, 0);
    CONSUME_S(sB, 1, af, 4); ISSUE_BATCH(sB, 8, 1);
    af = LD_A(8);
    CONSUME_S(sA, 0, af, 4); ISSUE_BATCH(sA, 9, 0);
    CONSUME_S(sB, 1, af, 4); ISSUE_BATCH(sB, 9, 1);
    af = LD_A(9);
    CONSUME_S(sA, 0, af, 4);
    CONSUME_S(sB, 1, af, 0);
    // queue EMPTY: nothing outstanding crosses the barrier.

    // gates + state update (z order: i, j, f, o)
    float h_val[2][4];
    #pragma unroll
    for (int ct = 0; ct < 2; ++ct) {
      #pragma unroll
      for (int q = 0; q < 4; ++q) {
        const float c_old = c_st[ct][q];
        const float ig = sigmoid_f(acc[ct][0][q] + bias_r[ct][0] + wi_r[ct] * c_old);
        const float fg = sigmoid_f(acc[ct][2][q] + bias_r[ct][2] + 1.0f + wf_r[ct] * c_old);
        const float jg = tanh_f(acc[ct][1][q] + bias_r[ct][1]);
        const float c_new = fg * c_old + ig * jg;
        const float og = sigmoid_f(acc[ct][3][q] + bias_r[ct][3] + wo_r[ct] * c_new);
        c_st[ct][q] = c_new;
        h_val[ct][q] = og * tanh_f(c_new);
      }
    }

    __syncthreads();  // all A_lds reads for step t done

    #pragma unroll
    for (int ct = 0; ct < 2; ++ct) {
      const int hc = (w * 2 + ct) * 16 + cl;
      #pragma unroll
      for (int q = 0; q < 4; ++q)
        A_lds[4 * kg + q][64 + hc] = f2bf(h_val[ct][q]);
    }
    if (havex) {
      const int r  = tid >> 5;
      const int f0 = (tid & 31) * 2;
      *(unsigned int*)&A_lds[r][f0] =
          (unsigned int)f2bf(xv.x) | ((unsigned int)f2bf(xv.y) << 16);
    }
    __syncthreads();
  }

  // safety drain before LDS overlay reuse
  asm volatile("s_waitcnt vmcnt(0)" ::: "memory");
  __builtin_amdgcn_sched_barrier(0);
  __syncthreads();

  // ---- epilogue: overlay scratch onto W_lds (all weight reads done) ----
  float* feat  = (float*)W_lds;            // [16][258]
  float* v_l   = feat + BROWS * 258;       // [16][128]
  float* q_l   = v_l + BROWS * 128;        // [16][128]
  float* ispos = q_l + BROWS * 128;        // [16]

  for (int i = tid; i < BROWS * H_DIM; i += 512) {
    const int r = i >> 8, hc = i & 255;
    feat[r * 258 + 2 + hc] = bf2f(A_lds[r][64 + hc]);
  }
  if (tid < BROWS) {
    feat[tid * 258 + 0] = head[(rb + tid) * 3 + 1];
    feat[tid * 258 + 1] = head[(rb + tid) * 3 + 2];
    ispos[tid] = head[(rb + tid) * 3 + 0];
  }
  __syncthreads();

  #pragma unroll
  for (int p = 0; p < 4; ++p) {
    const int idx = p * 512 + tid;
    const int r = idx >> 7, hh = idx & 127;
    float s3 = fc3_b[hh], s4 = fc4_b[hh];
    for (int k = 0; k < 258; ++k) {
      const float fv = feat[r * 258 + k];
      s3 += fv * fc3_w[k * 128 + hh];
      s4 += fv * fc4_w[k * 128 + hh];
    }
    v_l[r * 128 + hh] = fmaxf(s3, 0.0f);
    q_l[r * 128 + hh] = fmaxf(s4, 0.0f);
  }
  __syncthreads();

  if (tid < BROWS) {
    const int r = tid;
    float pa0 = sell_q_b[0], pa1 = sell_q_b[1];
    float ea0 = buy_q_b[0],  ea1 = buy_q_b[1];
    float sv = sell_v_b[0], bv = buy_v_b[0];
    for (int hh = 0; hh < 128; ++hh) {
      const float qv = q_l[r * 128 + hh], vv = v_l[r * 128 + hh];
      pa0 += qv * sell_q_w[hh * 2 + 0];
      pa1 += qv * sell_q_w[hh * 2 + 1];
      ea0 += qv * buy_q_w[hh * 2 + 0];
      ea1 += qv * buy_q_w[hh * 2 + 1];
      sv += vv * sell_v_w[hh];
      bv += vv * buy_v_w[hh];
    }
    const float pm = 0.5f * (pa0 + pa1), em = 0.5f * (ea0 + ea1);
    const float pq0 = pa0 - pm + sv, pq1 = pa1 - pm + sv;
    const float eq0 = ea0 - em + bv, eq1 = ea1 - em + bv;
    const float ip = ispos[r];
    out[(size_t)(rb + r) * 2 + 0] = (ip != 0.0f) ? pq0 : eq0;
    out[(size_t)(rb + r) * 2 + 1] = ((1.0f - ip) != 0.0f) ? pq1 : eq1;
  }
}

extern "C" void kernel_launch(void* const* d_in, const int* in_sizes, int n_in,
                              void* d_out, int out_size, void* d_ws, size_t ws_size,
                              hipStream_t stream) {
  (void)in_sizes; (void)n_in; (void)out_size; (void)ws_size;
  const float* history  = (const float*)d_in[0];
  const float* head     = (const float*)d_in[1];
  const float* Wk       = (const float*)d_in[2];
  const float* bias     = (const float*)d_in[3];
  const float* w_i      = (const float*)d_in[4];
  const float* w_f      = (const float*)d_in[5];
  const float* w_o      = (const float*)d_in[6];
  const float* fc3_w    = (const float*)d_in[7];
  const float* fc3_b    = (const float*)d_in[8];
  const float* fc4_w    = (const float*)d_in[9];
  const float* fc4_b    = (const float*)d_in[10];
  const float* sell_v_w = (const float*)d_in[11];
  const float* sell_v_b = (const float*)d_in[12];
  const float* sell_q_w = (const float*)d_in[13];
  const float* sell_q_b = (const float*)d_in[14];
  const float* buy_v_w  = (const float*)d_in[15];
  const float* buy_v_b  = (const float*)d_in[16];
  const float* buy_q_w  = (const float*)d_in[17];
  const float* buy_q_b  = (const float*)d_in[18];

  unsigned short* Wp = (unsigned short*)d_ws;  // 640 slots * 1 KiB = 640 KiB

  pack_w_kernel<<<NSLOTS, 64, 0, stream>>>(Wk, Wp);
  qlstm_kernel<<<B_TOTAL / BROWS, 512, 0, stream>>>(
      history, head, bias, w_i, w_f, w_o, Wp,
      fc3_w, fc3_b, fc4_w, fc4_b,
      sell_v_w, sell_v_b, sell_q_w, sell_q_b,
      buy_v_w, buy_v_b, buy_q_w, buy_q_b,
      (float*)d_out);
}

// Round 10
// 746.833 us; speedup vs baseline: 6.3869x; 1.0579x over previous
//
#include <hip/hip_runtime.h>
#include <stdint.h>

#define B_TOTAL 1024
#define T_STEPS 128
#define F_DIM   64
#define H_DIM   256
#define BROWS   16
#define APAD    324   // row stride 648B
#define NSLOTS  640   // 8 waves * 80 frags; slot = w*80 + kt*8 + ct*4 + g

typedef float f32x4 __attribute__((ext_vector_type(4)));
typedef short bf16x8 __attribute__((ext_vector_type(8)));

__device__ __forceinline__ unsigned short f2bf(float f) {
  unsigned int u = __float_as_uint(f);
  u += 0x7fffu + ((u >> 16) & 1u);
  return (unsigned short)(u >> 16);
}
__device__ __forceinline__ float bf2f(unsigned short b) {
  return __uint_as_float(((unsigned int)b) << 16);
}
__device__ __forceinline__ float sigmoid_f(float x) {
  return 1.0f / (1.0f + __expf(-x));
}
__device__ __forceinline__ float tanh_f(float x) {
  return 1.0f - 2.0f / (1.0f + __expf(2.0f * x));
}

// Pack kernel weights (320x1024 fp32 row-major) into bf16 MFMA-B fragments,
// wave-major: slot = w*80 + kt*8 + ct*4 + g; ntile = g*16 + w*2 + ct.
__global__ __launch_bounds__(64) void pack_w_kernel(const float* __restrict__ W,
                                                    unsigned short* __restrict__ Wp) {
  const int slot = blockIdx.x;
  const int w  = slot / 80, r = slot % 80;
  const int kt = r >> 3, ct = (r >> 2) & 1, g = r & 3;
  const int ntile = g * 16 + w * 2 + ct;
  const int l   = threadIdx.x;
  const int col = ntile * 16 + (l & 15);
  const int k0  = kt * 32 + (l >> 4) * 8;
  unsigned short* dst = Wp + ((size_t)slot * 64 + l) * 8;
  #pragma unroll
  for (int j = 0; j < 8; ++j)
    dst[j] = f2bf(W[(size_t)(k0 + j) * 1024 + col]);
}

// Opaque pins. PIN_V -> architected VGPRs; PIN_A -> AGPR half of the unified
// file (gfx950 MFMA reads A/B directly from AGPRs, ISA §10). Using AGPRs for
// the resident weight tier keeps arch-VGPR pressure under the 128 the
// allocator grants, eliminating round-9's scratch spill (WRITE_SIZE 3.2 MB).
#define PIN_V(x) asm volatile("" : "+v"(x))
#define PIN_A(x) asm volatile("" : "+a"(x))

// Issue 4 streamed fragments of (kt,ct). Wp is shorts; frag slot = 512 shorts.
// Buffers live ONLY within one loop iteration (no loop-carried async regs).
#define ISSUE_BATCH(buf, kt, ct) do {                                        \
    const unsigned short* _p = wp_wl + ((kt) * 8 + (ct) * 4) * 512;          \
    asm volatile("global_load_dwordx4 %0, %4, off\n\t"                       \
                 "global_load_dwordx4 %1, %4, off offset:1024\n\t"           \
                 "global_load_dwordx4 %2, %4, off offset:2048\n\t"           \
                 "global_load_dwordx4 %3, %4, off offset:3072"               \
                 : "=&v"(buf[0]), "=&v"(buf[1]), "=&v"(buf[2]), "=&v"(buf[3])\
                 : "v"(_p));                                                 \
  } while (0)

// Counted wait + sched fences (rule #18), 4 MFMAs into acc[ct].
#define CONSUME_S(buf, ct, afv, N) do {                                      \
    asm volatile("s_waitcnt vmcnt(" #N ")" ::: "memory");                    \
    __builtin_amdgcn_sched_barrier(0);                                       \
    acc[ct][0] = __builtin_amdgcn_mfma_f32_16x16x32_bf16(afv, buf[0], acc[ct][0], 0, 0, 0); \
    acc[ct][1] = __builtin_amdgcn_mfma_f32_16x16x32_bf16(afv, buf[1], acc[ct][1], 0, 0, 0); \
    acc[ct][2] = __builtin_amdgcn_mfma_f32_16x16x32_bf16(afv, buf[2], acc[ct][2], 0, 0, 0); \
    acc[ct][3] = __builtin_amdgcn_mfma_f32_16x16x32_bf16(afv, buf[3], acc[ct][3], 0, 0, 0); \
    __builtin_amdgcn_sched_barrier(0);                                       \
  } while (0)

#define LD_A(kt) (*(const bf16x8*)&A_lds[cl][(kt) * 32 + kg * 8])

__global__ __launch_bounds__(512, 1) void qlstm_kernel(
    const float* __restrict__ history, const float* __restrict__ head,
    const float* __restrict__ bias,
    const float* __restrict__ w_i, const float* __restrict__ w_f, const float* __restrict__ w_o,
    const unsigned short* __restrict__ Wp,
    const float* __restrict__ fc3_w, const float* __restrict__ fc3_b,
    const float* __restrict__ fc4_w, const float* __restrict__ fc4_b,
    const float* __restrict__ sell_v_w, const float* __restrict__ sell_v_b,
    const float* __restrict__ sell_q_w, const float* __restrict__ sell_q_b,
    const float* __restrict__ buy_v_w, const float* __restrict__ buy_v_b,
    const float* __restrict__ buy_q_w, const float* __restrict__ buy_q_b,
    float* __restrict__ out) {

  __shared__ unsigned short A_lds[BROWS][APAD];   // bf16: [r][k], k<64 = x_t, 64..319 = h
  __shared__ unsigned short W_lds[128 * 512];     // 128 KiB: kt4,5; slot s = w*16 + (kt-4)*8 + ct*4 + g

  const int tid = threadIdx.x;
  const int w   = tid >> 6;       // wave 0..7
  const int l   = tid & 63;
  const int cl  = l & 15;         // A-row / acc-col
  const int kg  = l >> 4;         // 0..3
  const int rb  = blockIdx.x * BROWS;

  const unsigned short* wp_wl = Wp + (size_t)(w * 80) * 512 + l * 8;
  const unsigned short* wl_l  = W_lds + (w * 16) * 512 + l * 8;

  // ---- preload LDS weight tier: frags f=32..47 (kt4,5) per wave ----
  for (int i = tid; i < 128 * 64; i += 512) {
    const int s = i >> 6, l2 = i & 63;
    const int fsrc = (s >> 4) * 80 + 32 + (s & 15);   // = w*80 + kt*8+ct*4+g, kt in {4,5}
    *(uint4*)&W_lds[((size_t)s * 64 + l2) * 8] =
        *(const uint4*)&Wp[((size_t)fsrc * 64 + l2) * 8];
  }

  // ---- register tier: kt 0..3 (32 frags = 128 regs), pinned.
  //      kt0..2 -> AGPRs (96), kt3 -> VGPRs (32). AGPR total with acc = 128;
  //      VGPR total ~119 -> no spill at 256/wave. ----
  bf16x8 wreg[4][2][4];
  #pragma unroll
  for (int kt = 0; kt < 4; ++kt)
    #pragma unroll
    for (int ct = 0; ct < 2; ++ct)
      #pragma unroll
      for (int g = 0; g < 4; ++g) {
        wreg[kt][ct][g] = *(const bf16x8*)(wp_wl + (kt * 8 + ct * 4 + g) * 512);
        if (kt < 3) PIN_A(wreg[kt][ct][g]); else PIN_V(wreg[kt][ct][g]);
      }

  // ---- zero A, stage x_0 ----
  for (int i = tid; i < BROWS * APAD; i += 512)
    ((unsigned short*)A_lds)[i] = 0;
  __syncthreads();
  {
    const int r  = tid >> 5;
    const int f0 = (tid & 31) * 2;
    const float2 xv0 = *(const float2*)&history[((size_t)(rb + r) * T_STEPS + 0) * F_DIM + f0];
    *(unsigned int*)&A_lds[r][f0] =
        (unsigned int)f2bf(xv0.x) | ((unsigned int)f2bf(xv0.y) << 16);
  }

  // ---- per-lane gate constants ----
  float bias_r[2][4], wi_r[2], wf_r[2], wo_r[2];
  #pragma unroll
  for (int ct = 0; ct < 2; ++ct) {
    const int hc = (w * 2 + ct) * 16 + cl;
    wi_r[ct] = w_i[hc]; wf_r[ct] = w_f[hc]; wo_r[ct] = w_o[hc];
    #pragma unroll
    for (int g = 0; g < 4; ++g) bias_r[ct][g] = bias[g * 256 + hc];
  }

  float c_st[2][4];
  #pragma unroll
  for (int ct = 0; ct < 2; ++ct)
    #pragma unroll
    for (int q = 0; q < 4; ++q) c_st[ct][q] = 0.0f;

  __syncthreads();

  // ---- the scan. All stream state is iteration-local (proven structure). ----
  for (int t = 0; t < T_STEPS; ++t) {
    // x prefetch for t+1: issued FIRST -> oldest in vmcnt queue, retired by
    // the first vmcnt(4) below.
    float2 xv;
    const bool havex = (t + 1 < T_STEPS);
    if (havex) {
      const float* xp =
          &history[((size_t)(rb + (tid >> 5)) * T_STEPS + (t + 1)) * F_DIM + (tid & 31) * 2];
      asm volatile("global_load_dwordx2 %0, %1, off" : "=&v"(xv) : "v"(xp));
    }

    f32x4 acc[2][4];
    #pragma unroll
    for (int ct = 0; ct < 2; ++ct)
      #pragma unroll
      for (int g = 0; g < 4; ++g)
        acc[ct][g] = (f32x4){0.f, 0.f, 0.f, 0.f};

    // stream tier = kt6..9 (8 batches), 2 buffers, in-iteration
    bf16x8 sA[4], sB[4];
    ISSUE_BATCH(sA, 6, 0);
    ISSUE_BATCH(sB, 6, 1);

    // reg tier kt0..3 (32 MFMAs cover L2 latency of the first batches)
    #pragma unroll
    for (int kt = 0; kt < 4; ++kt) {
      const bf16x8 afr = LD_A(kt);
      #pragma unroll
      for (int ct = 0; ct < 2; ++ct)
        #pragma unroll
        for (int g = 0; g < 4; ++g)
          acc[ct][g] =
              __builtin_amdgcn_mfma_f32_16x16x32_bf16(afr, wreg[kt][ct][g], acc[ct][g], 0, 0, 0);
    }

    // LDS tier kt4..5 (LDS pipe, parallel to the stream)
    #pragma unroll
    for (int kt = 4; kt < 6; ++kt) {
      const bf16x8 afr = LD_A(kt);
      #pragma unroll
      for (int ct = 0; ct < 2; ++ct)
        #pragma unroll
        for (int g = 0; g < 4; ++g) {
          const bf16x8 b = *(const bf16x8*)(wl_l + ((kt - 4) * 8 + ct * 4 + g) * 512);
          acc[ct][g] = __builtin_amdgcn_mfma_f32_16x16x32_bf16(afr, b, acc[ct][g], 0, 0, 0);
        }
    }

    // ladder: A,B alternation; each ISSUE refills the just-consumed buffer.
    // vmcnt trace: start 9 (x+sA+sB); each consume waits 4, each issue +4;
    // drains to 0 before the barrier.
    bf16x8 af;
    af = LD_A(6);
    CONSUME_S(sA, 0, af, 4); ISSUE_BATCH(sA, 7, 0);
    CONSUME_S(sB, 1, af, 4); ISSUE_BATCH(sB, 7, 1);
    af = LD_A(7);
    CONSUME_S(sA, 0, af, 4); ISSUE_BATCH(sA, 8, 0);
    CONSUME_S(sB, 1, af, 4); ISSUE_BATCH(sB, 8, 1);
    af = LD_A(8);
    CONSUME_S(sA, 0, af, 4); ISSUE_BATCH(sA, 9, 0);
    CONSUME_S(sB, 1, af, 4); ISSUE_BATCH(sB, 9, 1);
    af = LD_A(9);
    CONSUME_S(sA, 0, af, 4);
    CONSUME_S(sB, 1, af, 0);
    // queue EMPTY: nothing outstanding crosses the barrier.

    // gates + state update (z order: i, j, f, o)
    float h_val[2][4];
    #pragma unroll
    for (int ct = 0; ct < 2; ++ct) {
      #pragma unroll
      for (int q = 0; q < 4; ++q) {
        const float c_old = c_st[ct][q];
        const float ig = sigmoid_f(acc[ct][0][q] + bias_r[ct][0] + wi_r[ct] * c_old);
        const float fg = sigmoid_f(acc[ct][2][q] + bias_r[ct][2] + 1.0f + wf_r[ct] * c_old);
        const float jg = tanh_f(acc[ct][1][q] + bias_r[ct][1]);
        const float c_new = fg * c_old + ig * jg;
        const float og = sigmoid_f(acc[ct][3][q] + bias_r[ct][3] + wo_r[ct] * c_new);
        c_st[ct][q] = c_new;
        h_val[ct][q] = og * tanh_f(c_new);
      }
    }

    __syncthreads();  // all A_lds reads for step t done

    #pragma unroll
    for (int ct = 0; ct < 2; ++ct) {
      const int hc = (w * 2 + ct) * 16 + cl;
      #pragma unroll
      for (int q = 0; q < 4; ++q)
        A_lds[4 * kg + q][64 + hc] = f2bf(h_val[ct][q]);
    }
    if (havex) {
      const int r  = tid >> 5;
      const int f0 = (tid & 31) * 2;
      *(unsigned int*)&A_lds[r][f0] =
          (unsigned int)f2bf(xv.x) | ((unsigned int)f2bf(xv.y) << 16);
    }
    __syncthreads();
  }

  // safety drain before LDS overlay reuse
  asm volatile("s_waitcnt vmcnt(0)" ::: "memory");
  __builtin_amdgcn_sched_barrier(0);
  __syncthreads();

  // ---- epilogue: overlay scratch onto W_lds (all weight reads done) ----
  float* feat  = (float*)W_lds;            // [16][258]
  float* v_l   = feat + BROWS * 258;       // [16][128]
  float* q_l   = v_l + BROWS * 128;        // [16][128]
  float* ispos = q_l + BROWS * 128;        // [16]

  for (int i = tid; i < BROWS * H_DIM; i += 512) {
    const int r = i >> 8, hc = i & 255;
    feat[r * 258 + 2 + hc] = bf2f(A_lds[r][64 + hc]);
  }
  if (tid < BROWS) {
    feat[tid * 258 + 0] = head[(rb + tid) * 3 + 1];
    feat[tid * 258 + 1] = head[(rb + tid) * 3 + 2];
    ispos[tid] = head[(rb + tid) * 3 + 0];
  }
  __syncthreads();

  #pragma unroll
  for (int p = 0; p < 4; ++p) {
    const int idx = p * 512 + tid;
    const int r = idx >> 7, hh = idx & 127;
    float s3 = fc3_b[hh], s4 = fc4_b[hh];
    for (int k = 0; k < 258; ++k) {
      const float fv = feat[r * 258 + k];
      s3 += fv * fc3_w[k * 128 + hh];
      s4 += fv * fc4_w[k * 128 + hh];
    }
    v_l[r * 128 + hh] = fmaxf(s3, 0.0f);
    q_l[r * 128 + hh] = fmaxf(s4, 0.0f);
  }
  __syncthreads();

  if (tid < BROWS) {
    const int r = tid;
    float pa0 = sell_q_b[0], pa1 = sell_q_b[1];
    float ea0 = buy_q_b[0],  ea1 = buy_q_b[1];
    float sv = sell_v_b[0], bv = buy_v_b[0];
    for (int hh = 0; hh < 128; ++hh) {
      const float qv = q_l[r * 128 + hh], vv = v_l[r * 128 + hh];
      pa0 += qv * sell_q_w[hh * 2 + 0];
      pa1 += qv * sell_q_w[hh * 2 + 1];
      ea0 += qv * buy_q_w[hh * 2 + 0];
      ea1 += qv * buy_q_w[hh * 2 + 1];
      sv += vv * sell_v_w[hh];
      bv += vv * buy_v_w[hh];
    }
    const float pm = 0.5f * (pa0 + pa1), em = 0.5f * (ea0 + ea1);
    const float pq0 = pa0 - pm + sv, pq1 = pa1 - pm + sv;
    const float eq0 = ea0 - em + bv, eq1 = ea1 - em + bv;
    const float ip = ispos[r];
    out[(size_t)(rb + r) * 2 + 0] = (ip != 0.0f) ? pq0 : eq0;
    out[(size_t)(rb + r) * 2 + 1] = ((1.0f - ip) != 0.0f) ? pq1 : eq1;
  }
}

extern "C" void kernel_launch(void* const* d_in, const int* in_sizes, int n_in,
                              void* d_out, int out_size, void* d_ws, size_t ws_size,
                              hipStream_t stream) {
  (void)in_sizes; (void)n_in; (void)out_size; (void)ws_size;
  const float* history  = (const float*)d_in[0];
  const float* head     = (const float*)d_in[1];
  const float* Wk       = (const float*)d_in[2];
  const float* bias     = (const float*)d_in[3];
  const float* w_i      = (const float*)d_in[4];
  const float* w_f      = (const float*)d_in[5];
  const float* w_o      = (const float*)d_in[6];
  const float* fc3_w    = (const float*)d_in[7];
  const float* fc3_b    = (const float*)d_in[8];
  const float* fc4_w    = (const float*)d_in[9];
  const float* fc4_b    = (const float*)d_in[10];
  const float* sell_v_w = (const float*)d_in[11];
  const float* sell_v_b = (const float*)d_in[12];
  const float* sell_q_w = (const float*)d_in[13];
  const float* sell_q_b = (const float*)d_in[14];
  const float* buy_v_w  = (const float*)d_in[15];
  const float* buy_v_b  = (const float*)d_in[16];
  const float* buy_q_w  = (const float*)d_in[17];
  const float* buy_q_b  = (const float*)d_in[18];

  unsigned short* Wp = (unsigned short*)d_ws;  // 640 slots * 1 KiB = 640 KiB

  pack_w_kernel<<<NSLOTS, 64, 0, stream>>>(Wk, Wp);
  qlstm_kernel<<<B_TOTAL / BROWS, 512, 0, stream>>>(
      history, head, bias, w_i, w_f, w_o, Wp,
      fc3_w, fc3_b, fc4_w, fc4_b,
      sell_v_w, sell_v_b, sell_q_w, sell_q_b,
      buy_v_w, buy_v_b, buy_q_w, buy_q_b,
      (float*)d_out);
}